// Round 7
// baseline (208.505 us; speedup 1.0000x reference)
//
#include <hip/hip_runtime.h>
#include <hip/hip_bf16.h>
#include <stdint.h>

typedef __attribute__((ext_vector_type(4))) float f32x4;
typedef __attribute__((ext_vector_type(8))) __bf16 bf16x8;
typedef __attribute__((ext_vector_type(2))) unsigned int u32x2;
typedef __attribute__((ext_vector_type(4))) unsigned int u32x4;

#define N_NODES 16384
#define F_DIM   64
#define BM      128          // rows per block (8 waves x 16 rows)
#define BK      128          // K-step (doubled vs R5: halves barrier count & dead-window fraction)

__device__ inline unsigned cvtpk_bf16(float lo, float hi) {
    unsigned r;
    asm("v_cvt_pk_bf16_f32 %0, %1, %2" : "=v"(r) : "v"(lo), "v"(hi));
    return r;
}

// ---------------------------------------------------------------------------
// Kernel A: h = input @ W (fp32 compute), stored bf16 in MFMA B-frag layout:
// chunk[(kb*4+ct)*64 + l] (16B) = h[kb*32 + (l>>4)*8 + j][ct*16 + (l&15)]
// ---------------------------------------------------------------------------
__global__ __launch_bounds__(256) void dense_h(const float* __restrict__ inp,
                                               const float* __restrict__ W,
                                               short* __restrict__ hpack) {
    __shared__ float in_lds[64][64];
    __shared__ float wt_lds[64][68];
    const int t = threadIdx.x;
    const int blk = blockIdx.x;

#pragma unroll
    for (int i = 0; i < 4; ++i) {
        int n = i * 256 + t; int row = n >> 4; int c = n & 15;
        f32x4 v = *(const f32x4*)(inp + (size_t)(blk * 64 + row) * 64 + c * 4);
        *(f32x4*)(&in_lds[row][c * 4]) = v;
    }
#pragma unroll
    for (int i = 0; i < 4; ++i) {
        int n = i * 256 + t; int k = n >> 4; int c = n & 15;
        f32x4 v = *(const f32x4*)(W + k * 64 + c * 4);
        wt_lds[c * 4 + 0][k] = v.x; wt_lds[c * 4 + 1][k] = v.y;
        wt_lds[c * 4 + 2][k] = v.z; wt_lds[c * 4 + 3][k] = v.w;
    }
    __syncthreads();

#pragma unroll
    for (int cc = 0; cc < 2; ++cc) {
        int c = cc * 256 + t;
        int kbL = c >> 8; int ct = (c >> 6) & 3; int l = c & 63;
        int f  = ct * 16 + (l & 15);
        int r0 = kbL * 32 + (l >> 4) * 8;
        float acc[8] = {0, 0, 0, 0, 0, 0, 0, 0};
        for (int k = 0; k < 64; k += 4) {
            f32x4 wv = *(const f32x4*)(&wt_lds[f][k]);
#pragma unroll
            for (int j = 0; j < 8; ++j) {
                f32x4 iv = *(const f32x4*)(&in_lds[r0 + j][k]);
                acc[j] += iv.x * wv.x + iv.y * wv.y + iv.z * wv.z + iv.w * wv.w;
            }
        }
        u32x4 w4 = {cvtpk_bf16(acc[0], acc[1]), cvtpk_bf16(acc[2], acc[3]),
                    cvtpk_bf16(acc[4], acc[5]), cvtpk_bf16(acc[6], acc[7])};
        int kb = blk * 2 + kbL;
        *(u32x4*)(hpack + ((size_t)(kb * 4 + ct) * 64 + l) * 8) = w4;
    }
}

// ---------------------------------------------------------------------------
// Kernel B: partial[sp] = adj[:, k-range] @ h[k-range, :]
// R5 structure (block-wide coalesced LDS staging, XOR swizzle, raw s_barrier
// + lgkmcnt(0), inline B loads, 1-deep A prefetch, nontemporal adj, BM=128,
// 512 thr, 2 blocks/CU) with ONE change: BK 64->128. Halves barrier count
// and the dead-window fraction of each iteration.
// ---------------------------------------------------------------------------
__global__ __launch_bounds__(512, 4) void spmm_adj(const float* __restrict__ adj,
                                                   const short* __restrict__ hp,
                                                   float* __restrict__ out,
                                                   int kspan) {
    const int rb = blockIdx.x;
    const int sp = blockIdx.y;
    const int k0 = sp * kspan;
    const int iters = kspan >> 7;          // K-step 128
    const int t  = threadIdx.x;
    const int wv = t >> 6;                 // 0..7
    const int ln = t & 63;

    __shared__ short At[2][BM * BK];       // bf16, XOR-swizzled, 32KB each

    const size_t rowbase = (size_t)(rb * BM) * N_NODES;
    const int srow = t >> 5;               // 0..15: row within 16-row group
    const int scol = t & 31;               // 16B fp32 chunk within 512B row

    auto ldA = [&](int tt, f32x4* rv) {    // BM x 128 fp32 tile
        const float* base = adj + rowbase + (size_t)(k0 + tt * BK);
#pragma unroll
        for (int i = 0; i < 8; ++i) {
            int row = i * 16 + srow;
            rv[i] = __builtin_nontemporal_load(
                (const f32x4*)(base + (size_t)row * N_NODES + scol * 4));
        }
    };
    auto stA = [&](int buf, const f32x4* rv) {
#pragma unroll
        for (int i = 0; i < 8; ++i) {
            int row = i * 16 + srow;
            u32x2 w = {cvtpk_bf16(rv[i].x, rv[i].y), cvtpk_bf16(rv[i].z, rv[i].w)};
            int byte = row * 256 + ((scol * 8) ^ ((row & 7) << 4));
            *(u32x2*)((char*)At[buf] + byte) = w;
        }
    };

    f32x4 acc[4] = {{0,0,0,0},{0,0,0,0},{0,0,0,0},{0,0,0,0}};
    const int abase = (wv * 16 + (ln & 15)) * 256;   // row stride 256B
    const int aswz  = (ln & 7) << 4;
    const int koff  = (ln >> 4) * 16;

    f32x4 rv[8];
    ldA(0, rv);
    stA(0, rv);

    for (int tt = 0; tt < iters; ++tt) {
        const int cur = tt & 1;
        const bool more = (tt + 1 < iters);
        if (more) ldA(tt + 1, rv);                     // prefetch next A tile (in flight across barrier)
        asm volatile("s_waitcnt lgkmcnt(0)" ::: "memory");
        __builtin_amdgcn_s_barrier();                  // raw barrier: no vmcnt drain
#pragma unroll
        for (int kk = 0; kk < 4; ++kk) {               // 4 K-blocks of 32
            bf16x8 a = *(const bf16x8*)((const char*)At[cur] + abase + ((kk * 64 + koff) ^ aswz));
            const short* hbase = hp + ((size_t)((k0 >> 5) + tt * 4 + kk) * 4) * 512;
#pragma unroll
            for (int ct = 0; ct < 4; ++ct) {
                bf16x8 b = *(const bf16x8*)(hbase + ct * 512 + ln * 8);   // L2-hot
                acc[ct] = __builtin_amdgcn_mfma_f32_16x16x32_bf16(a, b, acc[ct], 0, 0, 0);
            }
        }
        if (more) stA(cur ^ 1, rv);
    }

    // epilogue: C layout col=lane&15, row=(lane>>4)*4+j
    float* o = out + (size_t)sp * ((size_t)N_NODES * F_DIM);
    const int orow0 = rb * BM + wv * 16 + (ln >> 4) * 4;
    const int col   = ln & 15;
#pragma unroll
    for (int ct = 0; ct < 4; ++ct)
#pragma unroll
        for (int j = 0; j < 4; ++j)
            o[(size_t)(orow0 + j) * F_DIM + ct * 16 + col] = acc[ct][j];
}

// ---------------------------------------------------------------------------
// Kernel C: out = sum_i partial[i] + bias
// ---------------------------------------------------------------------------
__global__ __launch_bounds__(256) void reduce_add(const float* __restrict__ part,
                                                  const float* __restrict__ bias,
                                                  float* __restrict__ out, int nsp) {
    int g = blockIdx.x * 256 + threadIdx.x;
    f32x4 s = {0, 0, 0, 0};
    for (int i = 0; i < nsp; ++i)
        s += *(const f32x4*)(part + (size_t)i * ((size_t)N_NODES * F_DIM) + (size_t)g * 4);
    f32x4 bv = *(const f32x4*)(bias + ((g * 4) & 63));
    *(f32x4*)(out + (size_t)g * 4) = s + bv;
}

extern "C" void kernel_launch(void* const* d_in, const int* in_sizes, int n_in,
                              void* d_out, int out_size, void* d_ws, size_t ws_size,
                              hipStream_t stream) {
    const float* inp = (const float*)d_in[0];
    const float* adj = (const float*)d_in[1];
    const float* W   = (const float*)d_in[2];
    const float* b   = (const float*)d_in[3];
    float* out = (float*)d_out;

    char*  ws = (char*)d_ws;
    const size_t HP = (size_t)N_NODES * F_DIM * sizeof(short);   // 2 MB packed bf16 h
    short* hpack = (short*)ws;
    float* partial = (float*)(ws + HP);
    const size_t P1 = (size_t)N_NODES * F_DIM * sizeof(float);   // 4 MB per partial

    dense_h<<<N_NODES / 64, 256, 0, stream>>>(inp, W, hpack);

    if (ws_size >= HP + 4 * P1) {
        dim3 g(N_NODES / BM, 4);           // 512 blocks = 2/CU, one residency round
        spmm_adj<<<g, 512, 0, stream>>>(adj, hpack, partial, N_NODES / 4);
        reduce_add<<<(N_NODES * F_DIM) / 1024, 256, 0, stream>>>(partial, b, out, 4);
    } else if (ws_size >= HP + P1) {
        dim3 g(N_NODES / BM, 1);
        spmm_adj<<<g, 512, 0, stream>>>(adj, hpack, partial, N_NODES);
        reduce_add<<<(N_NODES * F_DIM) / 1024, 256, 0, stream>>>(partial, b, out, 1);
    } else {
        dim3 g(N_NODES / BM, 1);
        spmm_adj<<<g, 512, 0, stream>>>(adj, hpack, out, N_NODES);
        reduce_add<<<(N_NODES * F_DIM) / 1024, 256, 0, stream>>>(out, b, out, 1);
    }
}

// Round 8
// 204.135 us; speedup vs baseline: 1.0214x; 1.0214x over previous
//
#include <hip/hip_runtime.h>
#include <hip/hip_bf16.h>
#include <stdint.h>

typedef __attribute__((ext_vector_type(4))) float f32x4;
typedef __attribute__((ext_vector_type(8))) __bf16 bf16x8;
typedef __attribute__((ext_vector_type(2))) unsigned int u32x2;
typedef __attribute__((ext_vector_type(4))) unsigned int u32x4;

#define N_NODES 16384
#define F_DIM   64
#define BM      128                     // rows per block (8 waves x 16 rows)
#define NF      (N_NODES * F_DIM)       // elements per partial

__device__ inline unsigned cvtpk_bf16(float lo, float hi) {
    unsigned r;
    asm("v_cvt_pk_bf16_f32 %0, %1, %2" : "=v"(r) : "v"(lo), "v"(hi));
    return r;
}
__device__ inline float bf_lo(unsigned u) { union { unsigned v; float f; } c; c.v = u << 16; return c.f; }
__device__ inline float bf_hi(unsigned u) { union { unsigned v; float f; } c; c.v = u & 0xffff0000u; return c.f; }

// ---------------------------------------------------------------------------
// Kernel A: h = input @ W (fp32 compute), stored bf16 in MFMA B-frag layout:
// chunk[(kb*4+ct)*64 + l] (16B) = h[kb*32 + (l>>4)*8 + j][ct*16 + (l&15)]
// ---------------------------------------------------------------------------
__global__ __launch_bounds__(256) void dense_h(const float* __restrict__ inp,
                                               const float* __restrict__ W,
                                               short* __restrict__ hpack) {
    __shared__ float in_lds[64][64];
    __shared__ float wt_lds[64][68];
    const int t = threadIdx.x;
    const int blk = blockIdx.x;

#pragma unroll
    for (int i = 0; i < 4; ++i) {
        int n = i * 256 + t; int row = n >> 4; int c = n & 15;
        f32x4 v = *(const f32x4*)(inp + (size_t)(blk * 64 + row) * 64 + c * 4);
        *(f32x4*)(&in_lds[row][c * 4]) = v;
    }
#pragma unroll
    for (int i = 0; i < 4; ++i) {
        int n = i * 256 + t; int k = n >> 4; int c = n & 15;
        f32x4 v = *(const f32x4*)(W + k * 64 + c * 4);
        wt_lds[c * 4 + 0][k] = v.x; wt_lds[c * 4 + 1][k] = v.y;
        wt_lds[c * 4 + 2][k] = v.z; wt_lds[c * 4 + 3][k] = v.w;
    }
    __syncthreads();

#pragma unroll
    for (int cc = 0; cc < 2; ++cc) {
        int c = cc * 256 + t;
        int kbL = c >> 8; int ct = (c >> 6) & 3; int l = c & 63;
        int f  = ct * 16 + (l & 15);
        int r0 = kbL * 32 + (l >> 4) * 8;
        float acc[8] = {0, 0, 0, 0, 0, 0, 0, 0};
        for (int k = 0; k < 64; k += 4) {
            f32x4 wv = *(const f32x4*)(&wt_lds[f][k]);
#pragma unroll
            for (int j = 0; j < 8; ++j) {
                f32x4 iv = *(const f32x4*)(&in_lds[r0 + j][k]);
                acc[j] += iv.x * wv.x + iv.y * wv.y + iv.z * wv.z + iv.w * wv.w;
            }
        }
        u32x4 w4 = {cvtpk_bf16(acc[0], acc[1]), cvtpk_bf16(acc[2], acc[3]),
                    cvtpk_bf16(acc[4], acc[5]), cvtpk_bf16(acc[6], acc[7])};
        int kb = blk * 2 + kbL;
        *(u32x4*)(hpack + ((size_t)(kb * 4 + ct) * 64 + l) * 8) = w4;
    }
}

// ---------------------------------------------------------------------------
// Kernel B: partial[sp] = adj[:, k-range] @ h[k-range, :]
// R5 structure verbatim (block-wide coalesced LDS staging, XOR swizzle, raw
// s_barrier + lgkmcnt(0), inline B loads, 1-deep A prefetch, nontemporal
// adj, BM=128/BK=64, 512 thr, 2 blocks/CU). Change vs R5: epilogue writes
// bf16 partials in MFMA-natural PACKED layout (contiguous u32x2 per ct,
// 512B/wave coalesced) instead of 16 scattered fp32 stores.
// ---------------------------------------------------------------------------
__global__ __launch_bounds__(512, 4) void spmm_adj(const float* __restrict__ adj,
                                                   const short* __restrict__ hp,
                                                   void* __restrict__ dst,
                                                   const float* __restrict__ bias,
                                                   int kspan, int direct) {
    const int rb = blockIdx.x;
    const int sp = blockIdx.y;
    const int k0 = sp * kspan;
    const int iters = kspan >> 6;          // K-step 64
    const int t  = threadIdx.x;
    const int wv = t >> 6;                 // 0..7
    const int ln = t & 63;

    __shared__ short At[2][BM * 64];       // bf16, XOR-swizzled, 16KB each

    const size_t rowbase = (size_t)(rb * BM) * N_NODES;
    const int srow = t >> 4;               // 0..31 staging row group
    const int scol = t & 15;               // 16B chunk within 256B row

    auto ldA = [&](int tt, f32x4* rv) {    // BM x 64 fp32 tile, 256B/row over 16 lanes
        const float* base = adj + rowbase + (size_t)(k0 + tt * 64);
#pragma unroll
        for (int i = 0; i < 4; ++i) {
            int row = i * 32 + srow;
            rv[i] = __builtin_nontemporal_load(
                (const f32x4*)(base + (size_t)row * N_NODES + scol * 4));
        }
    };
    auto stA = [&](int buf, const f32x4* rv) {
#pragma unroll
        for (int i = 0; i < 4; ++i) {
            int row = i * 32 + srow;
            u32x2 w = {cvtpk_bf16(rv[i].x, rv[i].y), cvtpk_bf16(rv[i].z, rv[i].w)};
            int byte = row * 128 + ((scol * 8) ^ ((row & 7) << 4));
            *(u32x2*)((char*)At[buf] + byte) = w;
        }
    };

    f32x4 acc[4] = {{0,0,0,0},{0,0,0,0},{0,0,0,0},{0,0,0,0}};
    const int abase = (wv * 16 + (ln & 15)) * 128;
    const int aswz  = (ln & 7) << 4;
    const int koff  = (ln >> 4) * 16;

    f32x4 rv[4];
    ldA(0, rv);
    stA(0, rv);

    for (int tt = 0; tt < iters; ++tt) {
        const int cur = tt & 1;
        const bool more = (tt + 1 < iters);
        if (more) ldA(tt + 1, rv);                     // prefetch next A tile
        asm volatile("s_waitcnt lgkmcnt(0)" ::: "memory");
        __builtin_amdgcn_s_barrier();                  // raw barrier: no vmcnt drain
#pragma unroll
        for (int ks2 = 0; ks2 < 2; ++ks2) {
            bf16x8 a = *(const bf16x8*)((const char*)At[cur] + abase + ((ks2 * 64 + koff) ^ aswz));
            const short* hbase = hp + ((size_t)((k0 >> 5) + tt * 2 + ks2) * 4) * 512;
#pragma unroll
            for (int ct = 0; ct < 4; ++ct) {
                bf16x8 b = *(const bf16x8*)(hbase + ct * 512 + ln * 8);   // L2-hot
                acc[ct] = __builtin_amdgcn_mfma_f32_16x16x32_bf16(a, b, acc[ct], 0, 0, 0);
            }
        }
        if (more) stA(cur ^ 1, rv);
    }

    if (direct) {
        // single-pass fallback: fp32 out with bias; C layout col=ln&15, row=(ln>>4)*4+j
        float* o = (float*)dst;
        const int orow0 = rb * BM + wv * 16 + (ln >> 4) * 4;
        const int col   = ln & 15;
#pragma unroll
        for (int ct = 0; ct < 4; ++ct)
#pragma unroll
            for (int j = 0; j < 4; ++j)
                o[(size_t)(orow0 + j) * F_DIM + ct * 16 + col] = acc[ct][j] + bias[ct * 16 + col];
    } else {
        // packed bf16 partial: element (rb,wv,ct,ln,j) at off ((((rb*8+wv)*4+ct)*64)+ln)*4 + j
        unsigned short* po = (unsigned short*)dst + (size_t)sp * NF
                           + ((size_t)(rb * 8 + wv) * 4) * 256 + ln * 4;
#pragma unroll
        for (int ct = 0; ct < 4; ++ct) {
            u32x2 w = {cvtpk_bf16(acc[ct][0], acc[ct][1]),
                       cvtpk_bf16(acc[ct][2], acc[ct][3])};
            *(u32x2*)(po + ct * 256) = w;               // 8B/lane, 512B/wave contiguous
        }
    }
}

// ---------------------------------------------------------------------------
// Kernel C: out = sum_sp packed_bf16_partial[sp] + bias  (does the scatter)
// ---------------------------------------------------------------------------
__global__ __launch_bounds__(256) void reduce_add(const unsigned short* __restrict__ part,
                                                  const float* __restrict__ bias,
                                                  float* __restrict__ out, int nsp) {
    int g = blockIdx.x * 256 + threadIdx.x;            // 0 .. NF/4-1, 4 values each
    int ln = g & 63, ct = (g >> 6) & 3, wvr = (g >> 8) & 7, rb = g >> 11;
    f32x4 s = {0, 0, 0, 0};
    for (int i = 0; i < nsp; ++i) {
        u32x2 w = *(const u32x2*)(part + (size_t)i * NF + (size_t)g * 4);
        s.x += bf_lo(w.x); s.y += bf_hi(w.x);
        s.z += bf_lo(w.y); s.w += bf_hi(w.y);
    }
    const int row0 = rb * BM + wvr * 16 + (ln >> 4) * 4;
    const int col  = ct * 16 + (ln & 15);
    const float bv = bias[col];
#pragma unroll
    for (int j = 0; j < 4; ++j)
        out[(size_t)(row0 + j) * F_DIM + col] = s[j] + bv;
}

extern "C" void kernel_launch(void* const* d_in, const int* in_sizes, int n_in,
                              void* d_out, int out_size, void* d_ws, size_t ws_size,
                              hipStream_t stream) {
    const float* inp = (const float*)d_in[0];
    const float* adj = (const float*)d_in[1];
    const float* W   = (const float*)d_in[2];
    const float* b   = (const float*)d_in[3];
    float* out = (float*)d_out;

    char*  ws = (char*)d_ws;
    const size_t HP = (size_t)NF * sizeof(short);        // 2 MB packed bf16 h
    short* hpack = (short*)ws;
    unsigned short* partial = (unsigned short*)(ws + HP);
    const size_t PB = (size_t)NF * sizeof(unsigned short);  // 2 MB per bf16 partial

    dense_h<<<N_NODES / 64, 256, 0, stream>>>(inp, W, hpack);

    if (ws_size >= HP + 4 * PB) {
        dim3 g(N_NODES / BM, 4);             // 512 blocks = 2/CU, one residency round
        spmm_adj<<<g, 512, 0, stream>>>(adj, hpack, partial, nullptr, N_NODES / 4, 0);
        reduce_add<<<NF / 1024, 256, 0, stream>>>(partial, b, out, 4);
    } else if (ws_size >= HP + PB) {
        dim3 g(N_NODES / BM, 1);
        spmm_adj<<<g, 512, 0, stream>>>(adj, hpack, partial, nullptr, N_NODES, 0);
        reduce_add<<<NF / 1024, 256, 0, stream>>>(partial, b, out, 1);
    } else {
        dim3 g(N_NODES / BM, 1);
        spmm_adj<<<g, 512, 0, stream>>>(adj, hpack, out, b, N_NODES, 1);
    }
}